// Round 1
// baseline (220.187 us; speedup 1.0000x reference)
//
#include <hip/hip_runtime.h>

typedef unsigned short u16;
typedef u16 u16x4 __attribute__((ext_vector_type(4)));
typedef u16 u16x8 __attribute__((ext_vector_type(8)));
typedef float f32x4 __attribute__((ext_vector_type(4)));
typedef __bf16 bf16x8 __attribute__((ext_vector_type(8)));

#define S_LEN 2048
#define D_DIM 1024

__device__ __forceinline__ u16 f2bf(float f) {
  unsigned int u = __builtin_bit_cast(unsigned int, f);
  u += 0x7FFFu + ((u >> 16) & 1u);
  return (u16)(u >> 16);
}

// ---------------------------------------------------------------- f32 -> bf16
__global__ __launch_bounds__(256) void f2b_kernel(const float* __restrict__ in,
                                                  u16* __restrict__ out, int n4) {
  int i = blockIdx.x * 256 + threadIdx.x;
  if (i < n4) {
    f32x4 v = *(const f32x4*)(in + (size_t)i * 4);
    u16x4 o;
    o[0] = f2bf(v[0]); o[1] = f2bf(v[1]); o[2] = f2bf(v[2]); o[3] = f2bf(v[3]);
    *(u16x4*)(out + (size_t)i * 4) = o;
  }
}

// --------------------------------------------- NT GEMM core: C = A * W^T
// A: [M][1024] bf16, W: [N][1024] bf16. Tile 128x128, BK=32, 256 thr (4 waves),
// each wave owns a 64x64 sub-tile = 4x4 frags of 16x16x32 MFMA.
__device__ __forceinline__ void gemm_core(const u16* __restrict__ A,
                                          const u16* __restrict__ W,
                                          int bm0, int bn0,
                                          u16* ldsA, u16* ldsB,
                                          f32x4 acc[4][4]) {
  const int tid = threadIdx.x;
  const int l = tid & 63;
  const int lr = l & 15, lk = l >> 4;
  const int w = tid >> 6;
  const int wr = w >> 1, wc = w & 1;
  for (int k0 = 0; k0 < 1024; k0 += 32) {
    __syncthreads();
#pragma unroll
    for (int it = 0; it < 2; ++it) {
      int c = it * 256 + tid;
      int row = c >> 2, ko = (c & 3) << 3;
      u16x8 va = *(const u16x8*)(A + (size_t)(bm0 + row) * 1024 + k0 + ko);
      u16x8 vb = *(const u16x8*)(W + (size_t)(bn0 + row) * 1024 + k0 + ko);
      *(u16x8*)(ldsA + row * 32 + ko) = va;
      *(u16x8*)(ldsB + row * 32 + ko) = vb;
    }
    __syncthreads();
    bf16x8 af[4], bfr[4];
#pragma unroll
    for (int m = 0; m < 4; ++m)
      af[m] = *(const bf16x8*)(ldsA + (wr * 64 + m * 16 + lr) * 32 + lk * 8);
#pragma unroll
    for (int n = 0; n < 4; ++n)
      bfr[n] = *(const bf16x8*)(ldsB + (wc * 64 + n * 16 + lr) * 32 + lk * 8);
#pragma unroll
    for (int m = 0; m < 4; ++m)
#pragma unroll
      for (int n = 0; n < 4; ++n)
        acc[m][n] = __builtin_amdgcn_mfma_f32_16x16x32_bf16(af[m], bfr[n], acc[m][n], 0, 0, 0);
  }
}

// --------------------------------------------- fused QKV projection
// z=0: Q -> Qf (f32 [4096][1024]); z=1: K -> Kf; z=2: V -> Vh bf16 [B,H,S,64]
__global__ __launch_bounds__(256) void qkv_gemm(const u16* __restrict__ xb,
    const u16* __restrict__ wq, const u16* __restrict__ wk, const u16* __restrict__ wv,
    const float* __restrict__ bq, const float* __restrict__ bk, const float* __restrict__ bv,
    float* __restrict__ Qf, float* __restrict__ Kf, u16* __restrict__ Vh) {
  __shared__ u16 ldsA[128 * 32];
  __shared__ u16 ldsB[128 * 32];
  const int z = blockIdx.z;
  const u16* W = (z == 0) ? wq : ((z == 1) ? wk : wv);
  const float* bias = (z == 0) ? bq : ((z == 1) ? bk : bv);
  const int bm0 = blockIdx.x * 128, bn0 = blockIdx.y * 128;
  const f32x4 zf = {0.f, 0.f, 0.f, 0.f};
  f32x4 acc[4][4];
#pragma unroll
  for (int m = 0; m < 4; ++m)
#pragma unroll
    for (int n = 0; n < 4; ++n) acc[m][n] = zf;
  gemm_core(xb, W, bm0, bn0, ldsA, ldsB, acc);
  const int tid = threadIdx.x, l = tid & 63, lr = l & 15, lk = l >> 4;
  const int w = tid >> 6, wr = w >> 1, wc = w & 1;
  float bcol[4];
#pragma unroll
  for (int n = 0; n < 4; ++n) bcol[n] = bias[bn0 + wc * 64 + n * 16 + lr];
  if (z < 2) {
    float* outp = z ? Kf : Qf;
#pragma unroll
    for (int m = 0; m < 4; ++m)
#pragma unroll
      for (int n = 0; n < 4; ++n)
#pragma unroll
        for (int r = 0; r < 4; ++r) {
          int row = bm0 + wr * 64 + m * 16 + lk * 4 + r;
          int col = bn0 + wc * 64 + n * 16 + lr;
          outp[(size_t)row * 1024 + col] = acc[m][n][r] + bcol[n];
        }
  } else {
#pragma unroll
    for (int m = 0; m < 4; ++m)
#pragma unroll
      for (int n = 0; n < 4; ++n)
#pragma unroll
        for (int r = 0; r < 4; ++r) {
          int row = bm0 + wr * 64 + m * 16 + lk * 4 + r;
          int col = bn0 + wc * 64 + n * 16 + lr;
          int b = row >> 11, s = row & 2047, hh = col >> 6, hd = col & 63;
          Vh[((size_t)((b * 16 + hh) << 11) + s) * 64 + hd] = f2bf(acc[m][n][r] + bcol[n]);
        }
  }
}

// --------------------------------------------- output projection
__global__ __launch_bounds__(256) void proj_gemm(const u16* __restrict__ ctx,
    const u16* __restrict__ wo, const float* __restrict__ bo, float* __restrict__ out) {
  __shared__ u16 ldsA[128 * 32];
  __shared__ u16 ldsB[128 * 32];
  const int bm0 = blockIdx.x * 128, bn0 = blockIdx.y * 128;
  const f32x4 zf = {0.f, 0.f, 0.f, 0.f};
  f32x4 acc[4][4];
#pragma unroll
  for (int m = 0; m < 4; ++m)
#pragma unroll
    for (int n = 0; n < 4; ++n) acc[m][n] = zf;
  gemm_core(ctx, wo, bm0, bn0, ldsA, ldsB, acc);
  const int tid = threadIdx.x, l = tid & 63, lr = l & 15, lk = l >> 4;
  const int w = tid >> 6, wr = w >> 1, wc = w & 1;
  float bcol[4];
#pragma unroll
  for (int n = 0; n < 4; ++n) bcol[n] = bo[bn0 + wc * 64 + n * 16 + lr];
#pragma unroll
  for (int m = 0; m < 4; ++m)
#pragma unroll
    for (int n = 0; n < 4; ++n)
#pragma unroll
      for (int r = 0; r < 4; ++r) {
        int row = bm0 + wr * 64 + m * 16 + lk * 4 + r;
        int col = bn0 + wc * 64 + n * 16 + lr;
        out[(size_t)row * 1024 + col] = acc[m][n][r] + bcol[n];
      }
}

// --------------------------------------------- RMSNorm + RoPE, f32 -> bf16 head layout
// grid (4096 rows, 2 tensors), block 256, 4 elems/thread
__global__ __launch_bounds__(256) void rmsrope(const float* __restrict__ Qf,
    const float* __restrict__ Kf, const float* __restrict__ gq, const float* __restrict__ gk,
    const float* __restrict__ fc, const float* __restrict__ fs,
    u16* __restrict__ Qh, u16* __restrict__ Kh) {
  const int row = blockIdx.x;
  const int which = blockIdx.y;
  const float* src = (which ? Kf : Qf) + (size_t)row * 1024;
  const float* g = which ? gk : gq;
  u16* dst = which ? Kh : Qh;
  const int t = threadIdx.x;
  f32x4 v = *(const f32x4*)(src + t * 4);
  float ss = v[0] * v[0] + v[1] * v[1] + v[2] * v[2] + v[3] * v[3];
#pragma unroll
  for (int mm = 1; mm < 64; mm <<= 1) ss += __shfl_xor(ss, mm);
  __shared__ float red[4];
  if ((t & 63) == 0) red[t >> 6] = ss;
  __syncthreads();
  float rstd = rsqrtf((red[0] + red[1] + red[2] + red[3]) * (1.0f / 1024.0f) + 1e-6f);
  int d = t * 4, hh = d >> 6, dh = d & 63, p = dh >> 1;
  int s = row & 2047, b = row >> 11;
  float c0 = fc[(s << 5) + p], s0 = fs[(s << 5) + p];
  float c1 = fc[(s << 5) + p + 1], s1 = fs[(s << 5) + p + 1];
  float x0 = v[0] * rstd * g[d];
  float x1 = v[1] * rstd * g[d + 1];
  float x2 = v[2] * rstd * g[d + 2];
  float x3 = v[3] * rstd * g[d + 3];
  u16x4 o;
  o[0] = f2bf(x0 * c0 - x1 * s0);
  o[1] = f2bf(x0 * s0 + x1 * c0);
  o[2] = f2bf(x2 * c1 - x3 * s1);
  o[3] = f2bf(x2 * s1 + x3 * c1);
  *(u16x4*)(dst + ((size_t)((b << 4) + hh) * 2048 + s) * 64 + dh) = o;
}

// --------------------------------------------- flash attention (non-causal)
// grid (32 q-tiles, 16 heads, 2 batch), 256 thr. 64 q-rows/WG, 16 per wave.
__global__ __launch_bounds__(256) void attn_kernel(const u16* __restrict__ Qh,
    const u16* __restrict__ Kh, const u16* __restrict__ Vh, u16* __restrict__ ctx) {
  __shared__ u16 Kt[64][72];       // [key][hd], padded stride 72 (16B aligned rows)
  __shared__ u16 Vt[64][72];       // [hd][key] (transposed), padded
  __shared__ u16 Pl[4][16][72];    // per-wave P scratch [qrow][key]
  const int tid = threadIdx.x;
  const int w = tid >> 6, l = tid & 63, lr = l & 15, lk = l >> 4;
  const int h = blockIdx.y, b = blockIdx.z;
  const int bh = b * 16 + h;
  const u16* Q = Qh + (size_t)bh * S_LEN * 64;
  const u16* K = Kh + (size_t)bh * S_LEN * 64;
  const u16* V = Vh + (size_t)bh * S_LEN * 64;
  const int q0 = blockIdx.x * 64;
  bf16x8 qf[2];
#pragma unroll
  for (int kh = 0; kh < 2; ++kh)
    qf[kh] = *(const bf16x8*)(Q + (size_t)(q0 + w * 16 + lr) * 64 + kh * 32 + lk * 8);
  const f32x4 zf = {0.f, 0.f, 0.f, 0.f};
  f32x4 O[4];
  float Mrun[4], lsum[4];
#pragma unroll
  for (int n = 0; n < 4; ++n) O[n] = zf;
#pragma unroll
  for (int r = 0; r < 4; ++r) { Mrun[r] = -1e30f; lsum[r] = 0.f; }
  const float CEXP = 0.18033688011112042f;  // 0.125 * log2(e)
  for (int kb = 0; kb < 32; ++kb) {
    __syncthreads();
#pragma unroll
    for (int it = 0; it < 2; ++it) {
      int idx = it * 256 + tid;
      int key = idx >> 3, hg = idx & 7;
      *(u16x8*)&Kt[key][hg * 8] = *(const u16x8*)(K + ((size_t)(kb * 64 + key) << 6) + hg * 8);
      int hd = idx & 63, kg = idx >> 6;
      u16x8 vv;
#pragma unroll
      for (int i = 0; i < 8; ++i)
        vv[i] = V[((size_t)(kb * 64 + kg * 8 + i) << 6) + hd];
      *(u16x8*)&Vt[hd][kg * 8] = vv;
    }
    __syncthreads();
    f32x4 sc[4];
#pragma unroll
    for (int n = 0; n < 4; ++n) sc[n] = zf;
#pragma unroll
    for (int n = 0; n < 4; ++n)
#pragma unroll
      for (int kh = 0; kh < 2; ++kh) {
        bf16x8 kf = *(const bf16x8*)(&Kt[n * 16 + lr][kh * 32 + lk * 8]);
        sc[n] = __builtin_amdgcn_mfma_f32_16x16x32_bf16(qf[kh], kf, sc[n], 0, 0, 0);
      }
    u16 pb[4][4];
#pragma unroll
    for (int r = 0; r < 4; ++r) {
      float bm = fmaxf(fmaxf(sc[0][r], sc[1][r]), fmaxf(sc[2][r], sc[3][r]));
#pragma unroll
      for (int mm = 1; mm < 16; mm <<= 1) bm = fmaxf(bm, __shfl_xor(bm, mm));
      float nM = fmaxf(Mrun[r], bm);
      float f = exp2f((Mrun[r] - nM) * CEXP);
      float rs = 0.f;
#pragma unroll
      for (int n = 0; n < 4; ++n) {
        float p = exp2f((sc[n][r] - nM) * CEXP);
        pb[n][r] = f2bf(p);
        rs += p;
      }
#pragma unroll
      for (int mm = 1; mm < 16; mm <<= 1) rs += __shfl_xor(rs, mm);
      lsum[r] = lsum[r] * f + rs;
      Mrun[r] = nM;
#pragma unroll
      for (int n = 0; n < 4; ++n) O[n][r] *= f;
    }
#pragma unroll
    for (int n = 0; n < 4; ++n)
#pragma unroll
      for (int r = 0; r < 4; ++r)
        Pl[w][lk * 4 + r][n * 16 + lr] = pb[n][r];
    // PV: P(16x64) @ V(64x64); Pl is wave-local, no barrier needed
#pragma unroll
    for (int kk = 0; kk < 2; ++kk) {
      bf16x8 pa = *(const bf16x8*)(&Pl[w][lr][kk * 32 + lk * 8]);
#pragma unroll
      for (int n = 0; n < 4; ++n) {
        bf16x8 vb = *(const bf16x8*)(&Vt[n * 16 + lr][kk * 32 + lk * 8]);
        O[n] = __builtin_amdgcn_mfma_f32_16x16x32_bf16(pa, vb, O[n], 0, 0, 0);
      }
    }
  }
#pragma unroll
  for (int n = 0; n < 4; ++n)
#pragma unroll
    for (int r = 0; r < 4; ++r) {
      int row = q0 + w * 16 + lk * 4 + r;
      float o = O[n][r] / lsum[r];
      ctx[((size_t)((b << 11) + row)) * 1024 + (h << 6) + n * 16 + lr] = f2bf(o);
    }
}

// ---------------------------------------------------------------- launch
extern "C" void kernel_launch(void* const* d_in, const int* in_sizes, int n_in,
                              void* d_out, int out_size, void* d_ws, size_t ws_size,
                              hipStream_t stream) {
  (void)in_sizes; (void)n_in; (void)out_size; (void)ws_size;
  const float* x  = (const float*)d_in[0];
  const float* Wq = (const float*)d_in[1];
  const float* bq = (const float*)d_in[2];
  const float* Wk = (const float*)d_in[3];
  const float* bk = (const float*)d_in[4];
  const float* Wv = (const float*)d_in[5];
  const float* bv = (const float*)d_in[6];
  const float* Wo = (const float*)d_in[7];
  const float* bo = (const float*)d_in[8];
  const float* gq = (const float*)d_in[9];
  const float* gk = (const float*)d_in[10];
  const float* fc = (const float*)d_in[11];
  const float* fs = (const float*)d_in[12];
  float* out = (float*)d_out;
  char* ws = (char*)d_ws;
  // workspace layout (bytes)
  u16*  xb  = (u16*)(ws + 0);           //  8388608  x bf16 [4096][1024]
  u16*  wqb = (u16*)(ws + 8388608);     //  2097152
  u16*  wkb = (u16*)(ws + 10485760);
  u16*  wvb = (u16*)(ws + 12582912);
  u16*  wob = (u16*)(ws + 14680064);
  float* Qf = (float*)(ws + 16777216);  // 16777216  f32 [4096][1024]
  float* Kf = (float*)(ws + 33554432);  // 16777216
  u16*  Qhb = (u16*)(ws + 50331648);    //  8388608  bf16 [B,H,S,64]
  u16*  Khb = (u16*)(ws + 58720256);
  u16*  Vhb = (u16*)(ws + 67108864);
  u16*  ctx = (u16*)(ws + 75497472);    //  8388608  bf16 [B,S,D]

  f2b_kernel<<<4096, 256, 0, stream>>>(x, xb, 1048576);
  f2b_kernel<<<1024, 256, 0, stream>>>(Wq, wqb, 262144);
  f2b_kernel<<<1024, 256, 0, stream>>>(Wk, wkb, 262144);
  f2b_kernel<<<1024, 256, 0, stream>>>(Wv, wvb, 262144);
  f2b_kernel<<<1024, 256, 0, stream>>>(Wo, wob, 262144);
  qkv_gemm<<<dim3(32, 8, 3), 256, 0, stream>>>(xb, wqb, wkb, wvb, bq, bk, bv, Qf, Kf, Vhb);
  rmsrope<<<dim3(4096, 2), 256, 0, stream>>>(Qf, Kf, gq, gk, fc, fs, Qhb, Khb);
  attn_kernel<<<dim3(32, 16, 2), 256, 0, stream>>>(Qhb, Khb, Vhb, ctx);
  proj_gemm<<<dim3(32, 8), 256, 0, stream>>>(ctx, wob, bo, out);
}

// Round 2
// 202.695 us; speedup vs baseline: 1.0863x; 1.0863x over previous
//
#include <hip/hip_runtime.h>

typedef unsigned short u16;
typedef u16 u16x4 __attribute__((ext_vector_type(4)));
typedef u16 u16x8 __attribute__((ext_vector_type(8)));
typedef float f32x4 __attribute__((ext_vector_type(4)));
typedef __bf16 bf16x8 __attribute__((ext_vector_type(8)));

#define GLOAD16(gp, lp)                                             \
  __builtin_amdgcn_global_load_lds(                                 \
      (const __attribute__((address_space(1))) void*)(gp),          \
      (__attribute__((address_space(3))) void*)(lp), 16, 0, 0)

__device__ __forceinline__ u16 f2bf(float f) {
  unsigned int u = __builtin_bit_cast(unsigned int, f);
  u += 0x7FFFu + ((u >> 16) & 1u);
  return (u16)(u >> 16);
}

// ---------------------------------------------------------------- f32 -> bf16
__global__ __launch_bounds__(256) void f2b_kernel(const float* __restrict__ in,
                                                  u16* __restrict__ out, int n4) {
  int i = blockIdx.x * 256 + threadIdx.x;
  if (i < n4) {
    f32x4 v = *(const f32x4*)(in + (size_t)i * 4);
    u16x4 o;
    o[0] = f2bf(v[0]); o[1] = f2bf(v[1]); o[2] = f2bf(v[2]); o[3] = f2bf(v[3]);
    *(u16x4*)(out + (size_t)i * 4) = o;
  }
}

// --------------------------------------------- NT GEMM core: C = A * W^T
// 128x128 tile, BK=32, 256 thr (4 waves). global_load_lds + 2-phase dbuf (T3 min).
__device__ __forceinline__ void gemm_core(const u16* __restrict__ A,
                                          const u16* __restrict__ W,
                                          int bm0, int bn0,
                                          u16* ldsA, u16* ldsB,
                                          f32x4 acc[4][4]) {
  const int tid = threadIdx.x;
  const int l = tid & 63;
  const int lr = l & 15, lk = l >> 4;
  const int w = tid >> 6;
  const int wr = w >> 1, wc = w & 1;
  const int srow = tid >> 2, sko = (tid & 3) << 3;
  auto stage = [&](int kt, int buf) {
#pragma unroll
    for (int it = 0; it < 2; ++it) {
      int row = it * 64 + srow;
      GLOAD16(A + (size_t)(bm0 + row) * 1024 + kt * 32 + sko,
              ldsA + buf * 4096 + (it * 256 + tid) * 8);
      GLOAD16(W + (size_t)(bn0 + row) * 1024 + kt * 32 + sko,
              ldsB + buf * 4096 + (it * 256 + tid) * 8);
    }
  };
  stage(0, 0);
  __syncthreads();
  int cur = 0;
  for (int kt = 0; kt < 32; ++kt) {
    if (kt + 1 < 32) stage(kt + 1, cur ^ 1);
    const u16* lA = ldsA + cur * 4096;
    const u16* lB = ldsB + cur * 4096;
    bf16x8 af[4], bfr[4];
#pragma unroll
    for (int m = 0; m < 4; ++m)
      af[m] = *(const bf16x8*)(lA + (wr * 64 + m * 16 + lr) * 32 + lk * 8);
#pragma unroll
    for (int n = 0; n < 4; ++n)
      bfr[n] = *(const bf16x8*)(lB + (wc * 64 + n * 16 + lr) * 32 + lk * 8);
#pragma unroll
    for (int m = 0; m < 4; ++m)
#pragma unroll
      for (int n = 0; n < 4; ++n)
        acc[m][n] = __builtin_amdgcn_mfma_f32_16x16x32_bf16(af[m], bfr[n], acc[m][n], 0, 0, 0);
    __syncthreads();
    cur ^= 1;
  }
}

// --------------------------------------------- fused QKV projection
// z=0: Q -> Qf (f32); z=1: K -> Kf; z=2: V -> V^T bf16 [B,H,64,S]
__global__ __launch_bounds__(256) void qkv_gemm(const u16* __restrict__ xb,
    const u16* __restrict__ wq, const u16* __restrict__ wk, const u16* __restrict__ wv,
    const float* __restrict__ bq, const float* __restrict__ bk, const float* __restrict__ bv,
    float* __restrict__ Qf, float* __restrict__ Kf, u16* __restrict__ Vt) {
  __shared__ u16 ldsA[2 * 4096];
  __shared__ u16 ldsB[2 * 4096];
  const int z = blockIdx.z;
  const u16* W = (z == 0) ? wq : ((z == 1) ? wk : wv);
  const float* bias = (z == 0) ? bq : ((z == 1) ? bk : bv);
  const int bm0 = blockIdx.x * 128, bn0 = blockIdx.y * 128;
  const f32x4 zf = {0.f, 0.f, 0.f, 0.f};
  f32x4 acc[4][4];
#pragma unroll
  for (int m = 0; m < 4; ++m)
#pragma unroll
    for (int n = 0; n < 4; ++n) acc[m][n] = zf;
  gemm_core(xb, W, bm0, bn0, ldsA, ldsB, acc);
  const int tid = threadIdx.x, l = tid & 63, lr = l & 15, lk = l >> 4;
  const int w = tid >> 6, wr = w >> 1, wc = w & 1;
  float bcol[4];
#pragma unroll
  for (int n = 0; n < 4; ++n) bcol[n] = bias[bn0 + wc * 64 + n * 16 + lr];
  if (z < 2) {
    float* outp = z ? Kf : Qf;
#pragma unroll
    for (int m = 0; m < 4; ++m)
#pragma unroll
      for (int n = 0; n < 4; ++n)
#pragma unroll
        for (int r = 0; r < 4; ++r) {
          int row = bm0 + wr * 64 + m * 16 + lk * 4 + r;
          int col = bn0 + wc * 64 + n * 16 + lr;
          outp[(size_t)row * 1024 + col] = acc[m][n][r] + bcol[n];
        }
  } else {
    // V^T: [B,H,64,2048]; 4 consecutive s per lane -> u16x4 store
#pragma unroll
    for (int m = 0; m < 4; ++m)
#pragma unroll
      for (int n = 0; n < 4; ++n) {
        int row = bm0 + wr * 64 + m * 16 + lk * 4;   // s base (r = 0..3)
        int col = bn0 + wc * 64 + n * 16 + lr;
        int b = row >> 11, s = row & 2047, hh = col >> 6, hd = col & 63;
        u16x4 o;
#pragma unroll
        for (int r = 0; r < 4; ++r) o[r] = f2bf(acc[m][n][r] + bcol[n]);
        *(u16x4*)(Vt + (((size_t)((b * 16 + hh) * 64 + hd)) << 11) + s) = o;
      }
  }
}

// --------------------------------------------- output projection
__global__ __launch_bounds__(256) void proj_gemm(const u16* __restrict__ ctx,
    const u16* __restrict__ wo, const float* __restrict__ bo, float* __restrict__ out) {
  __shared__ u16 ldsA[2 * 4096];
  __shared__ u16 ldsB[2 * 4096];
  const int bm0 = blockIdx.x * 128, bn0 = blockIdx.y * 128;
  const f32x4 zf = {0.f, 0.f, 0.f, 0.f};
  f32x4 acc[4][4];
#pragma unroll
  for (int m = 0; m < 4; ++m)
#pragma unroll
    for (int n = 0; n < 4; ++n) acc[m][n] = zf;
  gemm_core(ctx, wo, bm0, bn0, ldsA, ldsB, acc);
  const int tid = threadIdx.x, l = tid & 63, lr = l & 15, lk = l >> 4;
  const int w = tid >> 6, wr = w >> 1, wc = w & 1;
  float bcol[4];
#pragma unroll
  for (int n = 0; n < 4; ++n) bcol[n] = bo[bn0 + wc * 64 + n * 16 + lr];
#pragma unroll
  for (int m = 0; m < 4; ++m)
#pragma unroll
    for (int n = 0; n < 4; ++n)
#pragma unroll
      for (int r = 0; r < 4; ++r) {
        int row = bm0 + wr * 64 + m * 16 + lk * 4 + r;
        int col = bn0 + wc * 64 + n * 16 + lr;
        out[(size_t)row * 1024 + col] = acc[m][n][r] + bcol[n];
      }
}

// --------------------------------------------- RMSNorm + RoPE, f32 -> bf16 head layout
__global__ __launch_bounds__(256) void rmsrope(const float* __restrict__ Qf,
    const float* __restrict__ Kf, const float* __restrict__ gq, const float* __restrict__ gk,
    const float* __restrict__ fc, const float* __restrict__ fs,
    u16* __restrict__ Qh, u16* __restrict__ Kh) {
  const int row = blockIdx.x;
  const int which = blockIdx.y;
  const float* src = (which ? Kf : Qf) + (size_t)row * 1024;
  const float* g = which ? gk : gq;
  u16* dst = which ? Kh : Qh;
  const int t = threadIdx.x;
  f32x4 v = *(const f32x4*)(src + t * 4);
  float ss = v[0] * v[0] + v[1] * v[1] + v[2] * v[2] + v[3] * v[3];
#pragma unroll
  for (int mm = 1; mm < 64; mm <<= 1) ss += __shfl_xor(ss, mm);
  __shared__ float red[4];
  if ((t & 63) == 0) red[t >> 6] = ss;
  __syncthreads();
  float rstd = rsqrtf((red[0] + red[1] + red[2] + red[3]) * (1.0f / 1024.0f) + 1e-6f);
  int d = t * 4, hh = d >> 6, dh = d & 63, p = dh >> 1;
  int s = row & 2047, b = row >> 11;
  float c0 = fc[(s << 5) + p], s0 = fs[(s << 5) + p];
  float c1 = fc[(s << 5) + p + 1], s1 = fs[(s << 5) + p + 1];
  float x0 = v[0] * rstd * g[d];
  float x1 = v[1] * rstd * g[d + 1];
  float x2 = v[2] * rstd * g[d + 2];
  float x3 = v[3] * rstd * g[d + 3];
  u16x4 o;
  o[0] = f2bf(x0 * c0 - x1 * s0);
  o[1] = f2bf(x0 * s0 + x1 * c0);
  o[2] = f2bf(x2 * c1 - x3 * s1);
  o[3] = f2bf(x2 * s1 + x3 * c1);
  *(u16x4*)(dst + ((size_t)((b << 4) + hh) * 2048 + s) * 64 + dh) = o;
}

// --------------------------------------------- flash attention (non-causal)
// 512 blocks x 512 thr. 128 q-rows/WG, 8 waves x 16 q-rows. KVBLK=64 dbuf.
__global__ __launch_bounds__(512, 4) void attn_kernel(const u16* __restrict__ Qh,
    const u16* __restrict__ Kh, const u16* __restrict__ Vt, u16* __restrict__ ctx) {
  __shared__ u16 Kbuf[2][4096];   // [key][64] linear, source-XOR-swizzled chunks
  __shared__ u16 Vbuf[2][4096];   // [hd][64 keys] linear, source-XOR-swizzled
  __shared__ __attribute__((aligned(16))) float Pl[8][16][68];  // per-wave P f32
  const int tid = threadIdx.x;
  const int w = tid >> 6, l = tid & 63, lr = l & 15, lk = l >> 4;
  // XCD-clustered decode: all 16 q-tiles of one (h,b) share id%8 -> same XCD
  const int id = blockIdx.x;
  const int qt = (id >> 3) & 15;
  const int hb = (id & 7) | ((id >> 7) << 3);
  const int h = hb & 15, b = hb >> 4;
  const int bh = b * 16 + h;
  const u16* Q = Qh + (size_t)bh * 2048 * 64;
  const u16* K = Kh + (size_t)bh * 2048 * 64;
  const u16* V = Vt + (size_t)bh * 64 * 2048;
  const int q0 = qt * 128;
  const int srow = tid >> 3;                    // staging row (key for K, hd for V)
  const int kslot = (tid & 7) ^ (srow & 7);     // pre-swizzled 16B chunk
  bf16x8 qf[2];
#pragma unroll
  for (int kh = 0; kh < 2; ++kh)
    qf[kh] = *(const bf16x8*)(Q + (size_t)(q0 + w * 16 + lr) * 64 + kh * 32 + lk * 8);
  const f32x4 zf = {0.f, 0.f, 0.f, 0.f};
  f32x4 O[4];
  float Mrun[4], lsum[4];
#pragma unroll
  for (int n = 0; n < 4; ++n) O[n] = zf;
#pragma unroll
  for (int r = 0; r < 4; ++r) { Mrun[r] = -1e30f; lsum[r] = 0.f; }
  const float CEXP = 0.18033688011112042f;  // 0.125 * log2(e)
  GLOAD16(K + ((size_t)srow << 6) + kslot * 8, &Kbuf[0][tid * 8]);
  GLOAD16(V + ((size_t)srow << 11) + kslot * 8, &Vbuf[0][tid * 8]);
  __syncthreads();
  int cur = 0;
  for (int kb = 0; kb < 32; ++kb) {
    if (kb + 1 < 32) {
      GLOAD16(K + ((size_t)((kb + 1) * 64 + srow) << 6) + kslot * 8, &Kbuf[cur ^ 1][tid * 8]);
      GLOAD16(V + ((size_t)srow << 11) + (kb + 1) * 64 + kslot * 8, &Vbuf[cur ^ 1][tid * 8]);
    }
    // QK^T
    f32x4 sc[4];
#pragma unroll
    for (int n = 0; n < 4; ++n) sc[n] = zf;
#pragma unroll
    for (int n = 0; n < 4; ++n)
#pragma unroll
      for (int kh = 0; kh < 2; ++kh) {
        bf16x8 kf = *(const bf16x8*)(&Kbuf[cur][(n * 16 + lr) * 64 + (((kh * 4 + lk) ^ (lr & 7)) << 3)]);
        sc[n] = __builtin_amdgcn_mfma_f32_16x16x32_bf16(qf[kh], kf, sc[n], 0, 0, 0);
      }
    // online softmax (rows = lk*4+r, keys = n*16+lr), P -> f32 LDS
#pragma unroll
    for (int r = 0; r < 4; ++r) {
      float bm = fmaxf(fmaxf(sc[0][r], sc[1][r]), fmaxf(sc[2][r], sc[3][r]));
#pragma unroll
      for (int mm = 1; mm < 16; mm <<= 1) bm = fmaxf(bm, __shfl_xor(bm, mm));
      float nM = fmaxf(Mrun[r], bm);
      float f = exp2f((Mrun[r] - nM) * CEXP);
      float rs = 0.f;
#pragma unroll
      for (int n = 0; n < 4; ++n) {
        float p = exp2f((sc[n][r] - nM) * CEXP);
        Pl[w][lk * 4 + r][n * 16 + lr] = p;
        rs += p;
      }
#pragma unroll
      for (int mm = 1; mm < 16; mm <<= 1) rs += __shfl_xor(rs, mm);
      lsum[r] = lsum[r] * f + rs;
      Mrun[r] = nM;
#pragma unroll
      for (int n = 0; n < 4; ++n) O[n][r] *= f;
    }
    // PV: P(16x64) @ V(64x64); P read back + packed cvt to bf16
#pragma unroll
    for (int kk = 0; kk < 2; ++kk) {
      f32x4 p0 = *(const f32x4*)&Pl[w][lr][kk * 32 + lk * 8];
      f32x4 p1 = *(const f32x4*)&Pl[w][lr][kk * 32 + lk * 8 + 4];
      bf16x8 pa;
#pragma unroll
      for (int j = 0; j < 4; ++j) { pa[j] = (__bf16)p0[j]; pa[j + 4] = (__bf16)p1[j]; }
#pragma unroll
      for (int n = 0; n < 4; ++n) {
        bf16x8 vb = *(const bf16x8*)(&Vbuf[cur][(n * 16 + lr) * 64 + (((kk * 4 + lk) ^ (lr & 7)) << 3)]);
        O[n] = __builtin_amdgcn_mfma_f32_16x16x32_bf16(pa, vb, O[n], 0, 0, 0);
      }
    }
    __syncthreads();
    cur ^= 1;
  }
#pragma unroll
  for (int n = 0; n < 4; ++n)
#pragma unroll
    for (int r = 0; r < 4; ++r) {
      int row = q0 + w * 16 + lk * 4 + r;
      float o = O[n][r] / lsum[r];
      ctx[((size_t)((b << 11) + row)) * 1024 + (h << 6) + n * 16 + lr] = f2bf(o);
    }
}

// ---------------------------------------------------------------- launch
extern "C" void kernel_launch(void* const* d_in, const int* in_sizes, int n_in,
                              void* d_out, int out_size, void* d_ws, size_t ws_size,
                              hipStream_t stream) {
  (void)in_sizes; (void)n_in; (void)out_size; (void)ws_size;
  const float* x  = (const float*)d_in[0];
  const float* Wq = (const float*)d_in[1];
  const float* bq = (const float*)d_in[2];
  const float* Wk = (const float*)d_in[3];
  const float* bk = (const float*)d_in[4];
  const float* Wv = (const float*)d_in[5];
  const float* bv = (const float*)d_in[6];
  const float* Wo = (const float*)d_in[7];
  const float* bo = (const float*)d_in[8];
  const float* gq = (const float*)d_in[9];
  const float* gk = (const float*)d_in[10];
  const float* fc = (const float*)d_in[11];
  const float* fs = (const float*)d_in[12];
  float* out = (float*)d_out;
  char* ws = (char*)d_ws;
  u16*  xb  = (u16*)(ws + 0);           //  8 MB  x bf16 [4096][1024]
  u16*  wqb = (u16*)(ws + 8388608);
  u16*  wkb = (u16*)(ws + 10485760);
  u16*  wvb = (u16*)(ws + 12582912);
  u16*  wob = (u16*)(ws + 14680064);
  float* Qf = (float*)(ws + 16777216);  // 16 MB f32 [4096][1024]
  float* Kf = (float*)(ws + 33554432);  // 16 MB
  u16*  Qhb = (u16*)(ws + 50331648);    //  8 MB bf16 [B,H,S,64]
  u16*  Khb = (u16*)(ws + 58720256);    //  8 MB bf16 [B,H,S,64]
  u16*  Vtb = (u16*)(ws + 67108864);    //  8 MB bf16 [B,H,64,S]  (V transposed)
  u16*  ctx = (u16*)(ws + 75497472);    //  8 MB bf16 [B,S,D]

  f2b_kernel<<<4096, 256, 0, stream>>>(x, xb, 1048576);
  f2b_kernel<<<1024, 256, 0, stream>>>(Wq, wqb, 262144);
  f2b_kernel<<<1024, 256, 0, stream>>>(Wk, wkb, 262144);
  f2b_kernel<<<1024, 256, 0, stream>>>(Wv, wvb, 262144);
  f2b_kernel<<<1024, 256, 0, stream>>>(Wo, wob, 262144);
  qkv_gemm<<<dim3(32, 8, 3), 256, 0, stream>>>(xb, wqb, wkb, wvb, bq, bk, bv, Qf, Kf, Vtb);
  rmsrope<<<dim3(4096, 2), 256, 0, stream>>>(Qf, Kf, gq, gk, fc, fs, Qhb, Khb);
  attn_kernel<<<512, 512, 0, stream>>>(Qhb, Khb, Vtb, ctx);
  proj_gemm<<<dim3(32, 8), 256, 0, stream>>>(ctx, wob, bo, out);
}

// Round 3
// 165.656 us; speedup vs baseline: 1.3292x; 1.2236x over previous
//
#include <hip/hip_runtime.h>

typedef unsigned short u16;
typedef unsigned int u32;
typedef u16 u16x4 __attribute__((ext_vector_type(4)));
typedef u16 u16x8 __attribute__((ext_vector_type(8)));
typedef u32 u32x2 __attribute__((ext_vector_type(2)));
typedef float f32x4 __attribute__((ext_vector_type(4)));
typedef __bf16 bf16x2 __attribute__((ext_vector_type(2)));
typedef __bf16 bf16x8 __attribute__((ext_vector_type(8)));

#define GLOAD16(gp, lp)                                             \
  __builtin_amdgcn_global_load_lds(                                 \
      (const __attribute__((address_space(1))) void*)(gp),          \
      (__attribute__((address_space(3))) void*)(lp), 16, 0, 0)

__device__ __forceinline__ u16 f2bf(float f) {
  unsigned int u = __builtin_bit_cast(unsigned int, f);
  u += 0x7FFFu + ((u >> 16) & 1u);
  return (u16)(u >> 16);
}

// ---------------------------------------------------------------- f32 -> bf16
__global__ __launch_bounds__(256) void f2b_kernel(const float* __restrict__ in,
                                                  u16* __restrict__ out, int n4) {
  int i = blockIdx.x * 256 + threadIdx.x;
  if (i < n4) {
    f32x4 v = *(const f32x4*)(in + (size_t)i * 4);
    u16x4 o;
    o[0] = f2bf(v[0]); o[1] = f2bf(v[1]); o[2] = f2bf(v[2]); o[3] = f2bf(v[3]);
    *(u16x4*)(out + (size_t)i * 4) = o;
  }
}

// --------------------------------------------- NT GEMM core: C = A * W^T
// 128x128 tile, BK=32, 256 thr (4 waves). global_load_lds + 2-phase dbuf.
__device__ __forceinline__ void gemm_core(const u16* __restrict__ A,
                                          const u16* __restrict__ W,
                                          int bm0, int bn0,
                                          u16* ldsA, u16* ldsB,
                                          f32x4 acc[4][4]) {
  const int tid = threadIdx.x;
  const int l = tid & 63;
  const int lr = l & 15, lk = l >> 4;
  const int w = tid >> 6;
  const int wr = w >> 1, wc = w & 1;
  const int srow = tid >> 2, sko = (tid & 3) << 3;
  auto stage = [&](int kt, int buf) {
#pragma unroll
    for (int it = 0; it < 2; ++it) {
      int row = it * 64 + srow;
      GLOAD16(A + (size_t)(bm0 + row) * 1024 + kt * 32 + sko,
              ldsA + buf * 4096 + (it * 256 + tid) * 8);
      GLOAD16(W + (size_t)(bn0 + row) * 1024 + kt * 32 + sko,
              ldsB + buf * 4096 + (it * 256 + tid) * 8);
    }
  };
  stage(0, 0);
  __syncthreads();
  int cur = 0;
  for (int kt = 0; kt < 32; ++kt) {
    if (kt + 1 < 32) stage(kt + 1, cur ^ 1);
    const u16* lA = ldsA + cur * 4096;
    const u16* lB = ldsB + cur * 4096;
    bf16x8 af[4], bfr[4];
#pragma unroll
    for (int m = 0; m < 4; ++m)
      af[m] = *(const bf16x8*)(lA + (wr * 64 + m * 16 + lr) * 32 + lk * 8);
#pragma unroll
    for (int n = 0; n < 4; ++n)
      bfr[n] = *(const bf16x8*)(lB + (wc * 64 + n * 16 + lr) * 32 + lk * 8);
#pragma unroll
    for (int m = 0; m < 4; ++m)
#pragma unroll
      for (int n = 0; n < 4; ++n)
        acc[m][n] = __builtin_amdgcn_mfma_f32_16x16x32_bf16(af[m], bfr[n], acc[m][n], 0, 0, 0);
    __syncthreads();
    cur ^= 1;
  }
}

// --------------------------------------------- fused QKV projection
// z=0: Q -> Qf (f32); z=1: K -> Kf; z=2: V -> V^T bf16 [B,H,64,S]
__global__ __launch_bounds__(256) void qkv_gemm(const u16* __restrict__ xb,
    const u16* __restrict__ wq, const u16* __restrict__ wk, const u16* __restrict__ wv,
    const float* __restrict__ bq, const float* __restrict__ bk, const float* __restrict__ bv,
    float* __restrict__ Qf, float* __restrict__ Kf, u16* __restrict__ Vt) {
  __shared__ u16 ldsA[2 * 4096];
  __shared__ u16 ldsB[2 * 4096];
  const int z = blockIdx.z;
  const u16* W = (z == 0) ? wq : ((z == 1) ? wk : wv);
  const float* bias = (z == 0) ? bq : ((z == 1) ? bk : bv);
  const int bm0 = blockIdx.x * 128, bn0 = blockIdx.y * 128;
  const f32x4 zf = {0.f, 0.f, 0.f, 0.f};
  f32x4 acc[4][4];
#pragma unroll
  for (int m = 0; m < 4; ++m)
#pragma unroll
    for (int n = 0; n < 4; ++n) acc[m][n] = zf;
  gemm_core(xb, W, bm0, bn0, ldsA, ldsB, acc);
  const int tid = threadIdx.x, l = tid & 63, lr = l & 15, lk = l >> 4;
  const int w = tid >> 6, wr = w >> 1, wc = w & 1;
  float bcol[4];
#pragma unroll
  for (int n = 0; n < 4; ++n) bcol[n] = bias[bn0 + wc * 64 + n * 16 + lr];
  if (z < 2) {
    float* outp = z ? Kf : Qf;
#pragma unroll
    for (int m = 0; m < 4; ++m)
#pragma unroll
      for (int n = 0; n < 4; ++n)
#pragma unroll
        for (int r = 0; r < 4; ++r) {
          int row = bm0 + wr * 64 + m * 16 + lk * 4 + r;
          int col = bn0 + wc * 64 + n * 16 + lr;
          outp[(size_t)row * 1024 + col] = acc[m][n][r] + bcol[n];
        }
  } else {
    // V^T: [B,H,64,2048]; 4 consecutive s per lane -> u16x4 store
#pragma unroll
    for (int m = 0; m < 4; ++m)
#pragma unroll
      for (int n = 0; n < 4; ++n) {
        int row = bm0 + wr * 64 + m * 16 + lk * 4;   // s base (r = 0..3)
        int col = bn0 + wc * 64 + n * 16 + lr;
        int b = row >> 11, s = row & 2047, hh = col >> 6, hd = col & 63;
        u16x4 o;
#pragma unroll
        for (int r = 0; r < 4; ++r) o[r] = f2bf(acc[m][n][r] + bcol[n]);
        *(u16x4*)(Vt + (((size_t)((b * 16 + hh) * 64 + hd)) << 11) + s) = o;
      }
  }
}

// --------------------------------------------- output projection
__global__ __launch_bounds__(256) void proj_gemm(const u16* __restrict__ ctx,
    const u16* __restrict__ wo, const float* __restrict__ bo, float* __restrict__ out) {
  __shared__ u16 ldsA[2 * 4096];
  __shared__ u16 ldsB[2 * 4096];
  const int bm0 = blockIdx.x * 128, bn0 = blockIdx.y * 128;
  const f32x4 zf = {0.f, 0.f, 0.f, 0.f};
  f32x4 acc[4][4];
#pragma unroll
  for (int m = 0; m < 4; ++m)
#pragma unroll
    for (int n = 0; n < 4; ++n) acc[m][n] = zf;
  gemm_core(ctx, wo, bm0, bn0, ldsA, ldsB, acc);
  const int tid = threadIdx.x, l = tid & 63, lr = l & 15, lk = l >> 4;
  const int w = tid >> 6, wr = w >> 1, wc = w & 1;
  float bcol[4];
#pragma unroll
  for (int n = 0; n < 4; ++n) bcol[n] = bo[bn0 + wc * 64 + n * 16 + lr];
#pragma unroll
  for (int m = 0; m < 4; ++m)
#pragma unroll
    for (int n = 0; n < 4; ++n)
#pragma unroll
      for (int r = 0; r < 4; ++r) {
        int row = bm0 + wr * 64 + m * 16 + lk * 4 + r;
        int col = bn0 + wc * 64 + n * 16 + lr;
        out[(size_t)row * 1024 + col] = acc[m][n][r] + bcol[n];
      }
}

// --------------------------------------------- RMSNorm + RoPE, f32 -> bf16 head layout
__global__ __launch_bounds__(256) void rmsrope(const float* __restrict__ Qf,
    const float* __restrict__ Kf, const float* __restrict__ gq, const float* __restrict__ gk,
    const float* __restrict__ fc, const float* __restrict__ fs,
    u16* __restrict__ Qh, u16* __restrict__ Kh) {
  const int row = blockIdx.x;
  const int which = blockIdx.y;
  const float* src = (which ? Kf : Qf) + (size_t)row * 1024;
  const float* g = which ? gk : gq;
  u16* dst = which ? Kh : Qh;
  const int t = threadIdx.x;
  f32x4 v = *(const f32x4*)(src + t * 4);
  float ss = v[0] * v[0] + v[1] * v[1] + v[2] * v[2] + v[3] * v[3];
#pragma unroll
  for (int mm = 1; mm < 64; mm <<= 1) ss += __shfl_xor(ss, mm);
  __shared__ float red[4];
  if ((t & 63) == 0) red[t >> 6] = ss;
  __syncthreads();
  float rstd = rsqrtf((red[0] + red[1] + red[2] + red[3]) * (1.0f / 1024.0f) + 1e-6f);
  int d = t * 4, hh = d >> 6, dh = d & 63, p = dh >> 1;
  int s = row & 2047, b = row >> 11;
  float c0 = fc[(s << 5) + p], s0 = fs[(s << 5) + p];
  float c1 = fc[(s << 5) + p + 1], s1 = fs[(s << 5) + p + 1];
  float x0 = v[0] * rstd * g[d];
  float x1 = v[1] * rstd * g[d + 1];
  float x2 = v[2] * rstd * g[d + 2];
  float x3 = v[3] * rstd * g[d + 3];
  u16x4 o;
  o[0] = f2bf(x0 * c0 - x1 * s0);
  o[1] = f2bf(x0 * s0 + x1 * c0);
  o[2] = f2bf(x2 * c1 - x3 * s1);
  o[3] = f2bf(x2 * s1 + x3 * c1);
  *(u16x4*)(dst + ((size_t)((b << 4) + hh) * 2048 + s) * 64 + dh) = o;
}

// --------------------------------------------- flash attention (non-causal)
// 512 blocks x 512 thr, 8 waves x 16 q-rows. Swapped-operand MFMA: lane owns
// one q-row (lr) -> softmax & rescale are lane-local (2 shfl_xor per reduce).
__global__ __launch_bounds__(512, 4) void attn_kernel(const u16* __restrict__ Qh,
    const u16* __restrict__ Kh, const u16* __restrict__ Vt, u16* __restrict__ ctx) {
  __shared__ u16 Kbuf[2][4096];   // [key][64] linear, source-XOR-swizzled chunks
  __shared__ u16 Vbuf[2][4096];   // [hd][64 keys] linear, source-XOR-swizzled
  __shared__ __attribute__((aligned(16))) u32 Pl[8][16][36];  // per-wave P bf16x2
  const int tid = threadIdx.x;
  const int w = tid >> 6, l = tid & 63, lr = l & 15, lk = l >> 4;
  // XCD-clustered decode: all 16 q-tiles of one (h,b) share id%8 -> same XCD
  const int id = blockIdx.x;
  const int qt = (id >> 3) & 15;
  const int hb = (id & 7) | ((id >> 7) << 3);
  const int h = hb & 15, b = hb >> 4;
  const int bh = b * 16 + h;
  const u16* Q = Qh + (size_t)bh * 2048 * 64;
  const u16* K = Kh + (size_t)bh * 2048 * 64;
  const u16* V = Vt + (size_t)bh * 64 * 2048;
  const int q0 = qt * 128;
  const int srow = tid >> 3;                    // staging row (key for K, hd for V)
  const int kslot = (tid & 7) ^ (srow & 7);     // pre-swizzled 16B chunk
  bf16x8 qf[2];
#pragma unroll
  for (int kh = 0; kh < 2; ++kh)
    qf[kh] = *(const bf16x8*)(Q + (size_t)(q0 + w * 16 + lr) * 64 + kh * 32 + lk * 8);
  const f32x4 zf = {0.f, 0.f, 0.f, 0.f};
  f32x4 O[4];                                   // O[hd=16n+4lk+r][qrow=lr]
  float Mrun = -1e30f, lsum = 0.f;              // per-lane, q-row = lr
#pragma unroll
  for (int n = 0; n < 4; ++n) O[n] = zf;
  const float CEXP = 0.18033688011112042f;  // 0.125 * log2(e)
  GLOAD16(K + ((size_t)srow << 6) + kslot * 8, &Kbuf[0][tid * 8]);
  GLOAD16(V + ((size_t)srow << 11) + kslot * 8, &Vbuf[0][tid * 8]);
  __syncthreads();
  int cur = 0;
  for (int kb = 0; kb < 32; ++kb) {
    if (kb + 1 < 32) {
      GLOAD16(K + ((size_t)((kb + 1) * 64 + srow) << 6) + kslot * 8, &Kbuf[cur ^ 1][tid * 8]);
      GLOAD16(V + ((size_t)srow << 11) + (kb + 1) * 64 + kslot * 8, &Vbuf[cur ^ 1][tid * 8]);
    }
    // QK^T swapped: sc[n][r] = S[qrow=lr][key = 16n + 4lk + r]
    f32x4 sc[4];
#pragma unroll
    for (int n = 0; n < 4; ++n) sc[n] = zf;
#pragma unroll
    for (int n = 0; n < 4; ++n)
#pragma unroll
      for (int kh = 0; kh < 2; ++kh) {
        bf16x8 kf = *(const bf16x8*)(&Kbuf[cur][(n * 16 + lr) * 64 + (((kh * 4 + lk) ^ (lr & 7)) << 3)]);
        sc[n] = __builtin_amdgcn_mfma_f32_16x16x32_bf16(kf, qf[kh], sc[n], 0, 0, 0);
      }
    // online softmax, fully lane-local except 2+2 shfl_xor
    float bm = fmaxf(fmaxf(sc[0][0], sc[0][1]), fmaxf(sc[0][2], sc[0][3]));
#pragma unroll
    for (int n = 1; n < 4; ++n)
      bm = fmaxf(bm, fmaxf(fmaxf(sc[n][0], sc[n][1]), fmaxf(sc[n][2], sc[n][3])));
    bm = fmaxf(bm, __shfl_xor(bm, 16));
    bm = fmaxf(bm, __shfl_xor(bm, 32));
    if (!__all(bm <= Mrun + 8.0f)) {            // defer-max (T13)
      float nM = fmaxf(Mrun, bm);
      float f = exp2f((Mrun - nM) * CEXP);
      lsum *= f;
#pragma unroll
      for (int n = 0; n < 4; ++n)
#pragma unroll
        for (int r = 0; r < 4; ++r) O[n][r] *= f;
      Mrun = nM;
    }
    float rs = 0.f;
#pragma unroll
    for (int n = 0; n < 4; ++n) {
      u32 pw[2];
#pragma unroll
      for (int c = 0; c < 2; ++c) {
        float p0 = exp2f((sc[n][2 * c] - Mrun) * CEXP);
        float p1 = exp2f((sc[n][2 * c + 1] - Mrun) * CEXP);
        rs += p0 + p1;
        bf16x2 pp;
        pp[0] = (__bf16)p0; pp[1] = (__bf16)p1;
        pw[c] = __builtin_bit_cast(u32, pp);
      }
      u32x2 pv = {pw[0], pw[1]};
      *(u32x2*)&Pl[w][lr][8 * n + 2 * lk] = pv;  // keys (16n+4lk) pair-packed
    }
    rs += __shfl_xor(rs, 16);
    rs += __shfl_xor(rs, 32);
    lsum += rs;
    // PV swapped: O[hd][qrow] += V^T[hd][key] * P[qrow][key]
#pragma unroll
    for (int kk = 0; kk < 2; ++kk) {
      bf16x8 pa = *(const bf16x8*)&Pl[w][lr][16 * kk + 4 * lk];
#pragma unroll
      for (int n = 0; n < 4; ++n) {
        bf16x8 vb = *(const bf16x8*)(&Vbuf[cur][(n * 16 + lr) * 64 + (((kk * 4 + lk) ^ (lr & 7)) << 3)]);
        O[n] = __builtin_amdgcn_mfma_f32_16x16x32_bf16(vb, pa, O[n], 0, 0, 0);
      }
    }
    __syncthreads();
    cur ^= 1;
  }
  float inv = 1.0f / lsum;
  const size_t rowbase = ((size_t)((b << 11) + q0 + w * 16 + lr)) * 1024 + (h << 6);
#pragma unroll
  for (int n = 0; n < 4; ++n) {
    u16x4 o4;
#pragma unroll
    for (int r = 0; r < 4; ++r) o4[r] = f2bf(O[n][r] * inv);
    *(u16x4*)(ctx + rowbase + n * 16 + 4 * lk) = o4;
  }
}

// ---------------------------------------------------------------- launch
extern "C" void kernel_launch(void* const* d_in, const int* in_sizes, int n_in,
                              void* d_out, int out_size, void* d_ws, size_t ws_size,
                              hipStream_t stream) {
  (void)in_sizes; (void)n_in; (void)out_size; (void)ws_size;
  const float* x  = (const float*)d_in[0];
  const float* Wq = (const float*)d_in[1];
  const float* bq = (const float*)d_in[2];
  const float* Wk = (const float*)d_in[3];
  const float* bk = (const float*)d_in[4];
  const float* Wv = (const float*)d_in[5];
  const float* bv = (const float*)d_in[6];
  const float* Wo = (const float*)d_in[7];
  const float* bo = (const float*)d_in[8];
  const float* gq = (const float*)d_in[9];
  const float* gk = (const float*)d_in[10];
  const float* fc = (const float*)d_in[11];
  const float* fs = (const float*)d_in[12];
  float* out = (float*)d_out;
  char* ws = (char*)d_ws;
  u16*  xb  = (u16*)(ws + 0);           //  8 MB  x bf16 [4096][1024]
  u16*  wqb = (u16*)(ws + 8388608);
  u16*  wkb = (u16*)(ws + 10485760);
  u16*  wvb = (u16*)(ws + 12582912);
  u16*  wob = (u16*)(ws + 14680064);
  float* Qf = (float*)(ws + 16777216);  // 16 MB f32 [4096][1024]
  float* Kf = (float*)(ws + 33554432);  // 16 MB
  u16*  Qhb = (u16*)(ws + 50331648);    //  8 MB bf16 [B,H,S,64]
  u16*  Khb = (u16*)(ws + 58720256);    //  8 MB bf16 [B,H,S,64]
  u16*  Vtb = (u16*)(ws + 67108864);    //  8 MB bf16 [B,H,64,S]  (V transposed)
  u16*  ctx = (u16*)(ws + 75497472);    //  8 MB bf16 [B,S,D]

  f2b_kernel<<<4096, 256, 0, stream>>>(x, xb, 1048576);
  f2b_kernel<<<1024, 256, 0, stream>>>(Wq, wqb, 262144);
  f2b_kernel<<<1024, 256, 0, stream>>>(Wk, wkb, 262144);
  f2b_kernel<<<1024, 256, 0, stream>>>(Wv, wvb, 262144);
  f2b_kernel<<<1024, 256, 0, stream>>>(Wo, wob, 262144);
  qkv_gemm<<<dim3(32, 8, 3), 256, 0, stream>>>(xb, wqb, wkb, wvb, bq, bk, bv, Qf, Kf, Vtb);
  rmsrope<<<dim3(4096, 2), 256, 0, stream>>>(Qf, Kf, gq, gk, fc, fs, Qhb, Khb);
  attn_kernel<<<512, 512, 0, stream>>>(Qhb, Khb, Vtb, ctx);
  proj_gemm<<<dim3(32, 8), 256, 0, stream>>>(ctx, wob, bo, out);
}

// Round 4
// 157.688 us; speedup vs baseline: 1.3963x; 1.0505x over previous
//
#include <hip/hip_runtime.h>

typedef unsigned short u16;
typedef unsigned int u32;
typedef u16 u16x4 __attribute__((ext_vector_type(4)));
typedef u16 u16x8 __attribute__((ext_vector_type(8)));
typedef u32 u32x2 __attribute__((ext_vector_type(2)));
typedef float f32x4 __attribute__((ext_vector_type(4)));
typedef __bf16 bf16x2 __attribute__((ext_vector_type(2)));
typedef __bf16 bf16x8 __attribute__((ext_vector_type(8)));

#define GLOAD16(gp, lp)                                             \
  __builtin_amdgcn_global_load_lds(                                 \
      (const __attribute__((address_space(1))) void*)(gp),          \
      (__attribute__((address_space(3))) void*)(lp), 16, 0, 0)

__device__ __forceinline__ u16 f2bf(float f) {
  unsigned int u = __builtin_bit_cast(unsigned int, f);
  u += 0x7FFFu + ((u >> 16) & 1u);
  return (u16)(u >> 16);
}
__device__ __forceinline__ float bf2f(u16 h) {
  return __builtin_bit_cast(float, (u32)h << 16);
}

// ---------------------------------------------------------------- f32 -> bf16
__global__ __launch_bounds__(256) void f2b_kernel(const float* __restrict__ in,
                                                  u16* __restrict__ out, int n4) {
  int i = blockIdx.x * 256 + threadIdx.x;
  if (i < n4) {
    f32x4 v = *(const f32x4*)(in + (size_t)i * 4);
    u16x4 o;
    o[0] = f2bf(v[0]); o[1] = f2bf(v[1]); o[2] = f2bf(v[2]); o[3] = f2bf(v[3]);
    *(u16x4*)(out + (size_t)i * 4) = o;
  }
}

// all 4 weight matrices in one launch; dst regions contiguous (1M elems each)
__global__ __launch_bounds__(256) void f2bw_kernel(const float* __restrict__ s0,
    const float* __restrict__ s1, const float* __restrict__ s2,
    const float* __restrict__ s3, u16* __restrict__ dst) {
  const int y = blockIdx.y;
  const float* s = (y == 0) ? s0 : ((y == 1) ? s1 : ((y == 2) ? s2 : s3));
  int i = blockIdx.x * 256 + threadIdx.x;
  f32x4 v = *(const f32x4*)(s + (size_t)i * 4);
  u16x4 o;
  o[0] = f2bf(v[0]); o[1] = f2bf(v[1]); o[2] = f2bf(v[2]); o[3] = f2bf(v[3]);
  *(u16x4*)(dst + (size_t)y * 1048576 + (size_t)i * 4) = o;
}

// --------------------------------------------- NT GEMM core: C = A * W^T
// 128x128 tile, BK=32, 256 thr (4 waves). global_load_lds + 2-phase dbuf.
__device__ __forceinline__ void gemm_core(const u16* __restrict__ A,
                                          const u16* __restrict__ W,
                                          int bm0, int bn0,
                                          u16* ldsA, u16* ldsB,
                                          f32x4 acc[4][4]) {
  const int tid = threadIdx.x;
  const int l = tid & 63;
  const int lr = l & 15, lk = l >> 4;
  const int w = tid >> 6;
  const int wr = w >> 1, wc = w & 1;
  const int srow = tid >> 2, sko = (tid & 3) << 3;
  auto stage = [&](int kt, int buf) {
#pragma unroll
    for (int it = 0; it < 2; ++it) {
      int row = it * 64 + srow;
      GLOAD16(A + (size_t)(bm0 + row) * 1024 + kt * 32 + sko,
              ldsA + buf * 4096 + (it * 256 + tid) * 8);
      GLOAD16(W + (size_t)(bn0 + row) * 1024 + kt * 32 + sko,
              ldsB + buf * 4096 + (it * 256 + tid) * 8);
    }
  };
  stage(0, 0);
  __syncthreads();
  int cur = 0;
  for (int kt = 0; kt < 32; ++kt) {
    if (kt + 1 < 32) stage(kt + 1, cur ^ 1);
    const u16* lA = ldsA + cur * 4096;
    const u16* lB = ldsB + cur * 4096;
    bf16x8 af[4], bfr[4];
#pragma unroll
    for (int m = 0; m < 4; ++m)
      af[m] = *(const bf16x8*)(lA + (wr * 64 + m * 16 + lr) * 32 + lk * 8);
#pragma unroll
    for (int n = 0; n < 4; ++n)
      bfr[n] = *(const bf16x8*)(lB + (wc * 64 + n * 16 + lr) * 32 + lk * 8);
#pragma unroll
    for (int m = 0; m < 4; ++m)
#pragma unroll
      for (int n = 0; n < 4; ++n)
        acc[m][n] = __builtin_amdgcn_mfma_f32_16x16x32_bf16(af[m], bfr[n], acc[m][n], 0, 0, 0);
    __syncthreads();
    cur ^= 1;
  }
}

// --------------------------------------------- fused QKV projection
// z=0: Q -> Qb (bf16 [4096][1024]); z=1: K -> Kb; z=2: V -> V^T bf16 [B,H,64,S]
__global__ __launch_bounds__(256) void qkv_gemm(const u16* __restrict__ xb,
    const u16* __restrict__ wq, const u16* __restrict__ wk, const u16* __restrict__ wv,
    const float* __restrict__ bq, const float* __restrict__ bk, const float* __restrict__ bv,
    u16* __restrict__ Qb, u16* __restrict__ Kb, u16* __restrict__ Vt) {
  __shared__ u16 ldsA[2 * 4096];
  __shared__ u16 ldsB[2 * 4096];
  const int z = blockIdx.z;
  const u16* W = (z == 0) ? wq : ((z == 1) ? wk : wv);
  const float* bias = (z == 0) ? bq : ((z == 1) ? bk : bv);
  const int bm0 = blockIdx.x * 128, bn0 = blockIdx.y * 128;
  const f32x4 zf = {0.f, 0.f, 0.f, 0.f};
  f32x4 acc[4][4];
#pragma unroll
  for (int m = 0; m < 4; ++m)
#pragma unroll
    for (int n = 0; n < 4; ++n) acc[m][n] = zf;
  gemm_core(xb, W, bm0, bn0, ldsA, ldsB, acc);
  const int tid = threadIdx.x, l = tid & 63, lr = l & 15, lk = l >> 4;
  const int w = tid >> 6, wr = w >> 1, wc = w & 1;
  float bcol[4];
#pragma unroll
  for (int n = 0; n < 4; ++n) bcol[n] = bias[bn0 + wc * 64 + n * 16 + lr];
  if (z < 2) {
    u16* outp = z ? Kb : Qb;
#pragma unroll
    for (int m = 0; m < 4; ++m)
#pragma unroll
      for (int n = 0; n < 4; ++n)
#pragma unroll
        for (int r = 0; r < 4; ++r) {
          int row = bm0 + wr * 64 + m * 16 + lk * 4 + r;
          int col = bn0 + wc * 64 + n * 16 + lr;
          outp[(size_t)row * 1024 + col] = f2bf(acc[m][n][r] + bcol[n]);
        }
  } else {
    // V^T: [B,H,64,2048]; 4 consecutive s per lane -> u16x4 store
#pragma unroll
    for (int m = 0; m < 4; ++m)
#pragma unroll
      for (int n = 0; n < 4; ++n) {
        int row = bm0 + wr * 64 + m * 16 + lk * 4;   // s base (r = 0..3)
        int col = bn0 + wc * 64 + n * 16 + lr;
        int b = row >> 11, s = row & 2047, hh = col >> 6, hd = col & 63;
        u16x4 o;
#pragma unroll
        for (int r = 0; r < 4; ++r) o[r] = f2bf(acc[m][n][r] + bcol[n]);
        *(u16x4*)(Vt + (((size_t)((b * 16 + hh) * 64 + hd)) << 11) + s) = o;
      }
  }
}

// --------------------------------------------- output projection
__global__ __launch_bounds__(256) void proj_gemm(const u16* __restrict__ ctx,
    const u16* __restrict__ wo, const float* __restrict__ bo, float* __restrict__ out) {
  __shared__ u16 ldsA[2 * 4096];
  __shared__ u16 ldsB[2 * 4096];
  const int bm0 = blockIdx.x * 128, bn0 = blockIdx.y * 128;
  const f32x4 zf = {0.f, 0.f, 0.f, 0.f};
  f32x4 acc[4][4];
#pragma unroll
  for (int m = 0; m < 4; ++m)
#pragma unroll
    for (int n = 0; n < 4; ++n) acc[m][n] = zf;
  gemm_core(ctx, wo, bm0, bn0, ldsA, ldsB, acc);
  const int tid = threadIdx.x, l = tid & 63, lr = l & 15, lk = l >> 4;
  const int w = tid >> 6, wr = w >> 1, wc = w & 1;
  float bcol[4];
#pragma unroll
  for (int n = 0; n < 4; ++n) bcol[n] = bo[bn0 + wc * 64 + n * 16 + lr];
#pragma unroll
  for (int m = 0; m < 4; ++m)
#pragma unroll
    for (int n = 0; n < 4; ++n)
#pragma unroll
      for (int r = 0; r < 4; ++r) {
        int row = bm0 + wr * 64 + m * 16 + lk * 4 + r;
        int col = bn0 + wc * 64 + n * 16 + lr;
        out[(size_t)row * 1024 + col] = acc[m][n][r] + bcol[n];
      }
}

// --------------------------------------------- RMSNorm + RoPE (bf16 in/out)
// which==0 (q): also fold 0.125*log2(e) so attn scores are exp2-domain ready.
__global__ __launch_bounds__(256) void rmsrope(const u16* __restrict__ Qb,
    const u16* __restrict__ Kb, const float* __restrict__ gq, const float* __restrict__ gk,
    const float* __restrict__ fc, const float* __restrict__ fs,
    u16* __restrict__ Qh, u16* __restrict__ Kh) {
  const int row = blockIdx.x;
  const int which = blockIdx.y;
  const u16* src = (which ? Kb : Qb) + (size_t)row * 1024;
  const float* g = which ? gk : gq;
  u16* dst = which ? Kh : Qh;
  const int t = threadIdx.x;
  u16x4 raw = *(const u16x4*)(src + t * 4);
  float v0 = bf2f(raw[0]), v1 = bf2f(raw[1]), v2 = bf2f(raw[2]), v3 = bf2f(raw[3]);
  float ss = v0 * v0 + v1 * v1 + v2 * v2 + v3 * v3;
#pragma unroll
  for (int mm = 1; mm < 64; mm <<= 1) ss += __shfl_xor(ss, mm);
  __shared__ float red[4];
  if ((t & 63) == 0) red[t >> 6] = ss;
  __syncthreads();
  float rstd = rsqrtf((red[0] + red[1] + red[2] + red[3]) * (1.0f / 1024.0f) + 1e-6f);
  if (!which) rstd *= 0.18033688011112042f;   // 0.125 * log2(e) folded into q
  int d = t * 4, hh = d >> 6, dh = d & 63, p = dh >> 1;
  int s = row & 2047, b = row >> 11;
  float c0 = fc[(s << 5) + p], s0 = fs[(s << 5) + p];
  float c1 = fc[(s << 5) + p + 1], s1 = fs[(s << 5) + p + 1];
  float x0 = v0 * rstd * g[d];
  float x1 = v1 * rstd * g[d + 1];
  float x2 = v2 * rstd * g[d + 2];
  float x3 = v3 * rstd * g[d + 3];
  u16x4 o;
  o[0] = f2bf(x0 * c0 - x1 * s0);
  o[1] = f2bf(x0 * s0 + x1 * c0);
  o[2] = f2bf(x2 * c1 - x3 * s1);
  o[3] = f2bf(x2 * s1 + x3 * c1);
  *(u16x4*)(dst + ((size_t)((b << 4) + hh) * 2048 + s) * 64 + dh) = o;
}

// --------------------------------------------- flash attention (non-causal)
// 512 blocks x 512 thr, 8 waves x 16 q-rows. Swapped-operand MFMA; scores are
// pre-scaled to exp2 domain (q carries 0.125*log2e).
__global__ __launch_bounds__(512, 4) void attn_kernel(const u16* __restrict__ Qh,
    const u16* __restrict__ Kh, const u16* __restrict__ Vt, u16* __restrict__ ctx) {
  __shared__ u16 Kbuf[2][4096];   // [key][64] linear, source-XOR-swizzled chunks
  __shared__ u16 Vbuf[2][4096];   // [hd][64 keys] linear, source-XOR-swizzled
  __shared__ __attribute__((aligned(16))) u32 Pl[8][16][36];  // per-wave P bf16x2
  const int tid = threadIdx.x;
  const int w = tid >> 6, l = tid & 63, lr = l & 15, lk = l >> 4;
  const int id = blockIdx.x;
  const int qt = (id >> 3) & 15;
  const int hb = (id & 7) | ((id >> 7) << 3);
  const int h = hb & 15, b = hb >> 4;
  const int bh = b * 16 + h;
  const u16* Q = Qh + (size_t)bh * 2048 * 64;
  const u16* K = Kh + (size_t)bh * 2048 * 64;
  const u16* V = Vt + (size_t)bh * 64 * 2048;
  const int q0 = qt * 128;
  const int srow = tid >> 3;
  const int kslot = (tid & 7) ^ (srow & 7);
  bf16x8 qf[2];
#pragma unroll
  for (int kh = 0; kh < 2; ++kh)
    qf[kh] = *(const bf16x8*)(Q + (size_t)(q0 + w * 16 + lr) * 64 + kh * 32 + lk * 8);
  const f32x4 zf = {0.f, 0.f, 0.f, 0.f};
  f32x4 O[4];                                   // O[hd=16n+4lk+r][qrow=lr]
  float Mrun = -1e30f, lsum = 0.f;
#pragma unroll
  for (int n = 0; n < 4; ++n) O[n] = zf;
  GLOAD16(K + ((size_t)srow << 6) + kslot * 8, &Kbuf[0][tid * 8]);
  GLOAD16(V + ((size_t)srow << 11) + kslot * 8, &Vbuf[0][tid * 8]);
  __syncthreads();
  int cur = 0;
  for (int kb = 0; kb < 32; ++kb) {
    if (kb + 1 < 32) {
      GLOAD16(K + ((size_t)((kb + 1) * 64 + srow) << 6) + kslot * 8, &Kbuf[cur ^ 1][tid * 8]);
      GLOAD16(V + ((size_t)srow << 11) + (kb + 1) * 64 + kslot * 8, &Vbuf[cur ^ 1][tid * 8]);
    }
    // QK^T swapped: sc[n][r] = S[qrow=lr][key = 16n + 4lk + r]  (exp2 domain)
    f32x4 sc[4];
#pragma unroll
    for (int n = 0; n < 4; ++n) sc[n] = zf;
    __builtin_amdgcn_s_setprio(1);
#pragma unroll
    for (int n = 0; n < 4; ++n)
#pragma unroll
      for (int kh = 0; kh < 2; ++kh) {
        bf16x8 kf = *(const bf16x8*)(&Kbuf[cur][(n * 16 + lr) * 64 + (((kh * 4 + lk) ^ (lr & 7)) << 3)]);
        sc[n] = __builtin_amdgcn_mfma_f32_16x16x32_bf16(kf, qf[kh], sc[n], 0, 0, 0);
      }
    __builtin_amdgcn_s_setprio(0);
    // online softmax, lane-local except 2+2 shfl_xor
    float bm = fmaxf(fmaxf(sc[0][0], sc[0][1]), fmaxf(sc[0][2], sc[0][3]));
#pragma unroll
    for (int n = 1; n < 4; ++n)
      bm = fmaxf(bm, fmaxf(fmaxf(sc[n][0], sc[n][1]), fmaxf(sc[n][2], sc[n][3])));
    bm = fmaxf(bm, __shfl_xor(bm, 16));
    bm = fmaxf(bm, __shfl_xor(bm, 32));
    if (!__all(bm <= Mrun + 1.4427f)) {         // defer-max (T13), exp2 units
      float nM = fmaxf(Mrun, bm);
      float f = exp2f(Mrun - nM);
      lsum *= f;
#pragma unroll
      for (int n = 0; n < 4; ++n)
#pragma unroll
        for (int r = 0; r < 4; ++r) O[n][r] *= f;
      Mrun = nM;
    }
    float rs = 0.f;
#pragma unroll
    for (int n = 0; n < 4; ++n) {
      u32 pw[2];
#pragma unroll
      for (int c = 0; c < 2; ++c) {
        float p0 = exp2f(sc[n][2 * c] - Mrun);
        float p1 = exp2f(sc[n][2 * c + 1] - Mrun);
        rs += p0 + p1;
        bf16x2 pp;
        pp[0] = (__bf16)p0; pp[1] = (__bf16)p1;
        pw[c] = __builtin_bit_cast(u32, pp);
      }
      u32x2 pv = {pw[0], pw[1]};
      *(u32x2*)&Pl[w][lr][8 * n + 2 * lk] = pv;
    }
    rs += __shfl_xor(rs, 16);
    rs += __shfl_xor(rs, 32);
    lsum += rs;
    // PV swapped: O[hd][qrow] += V^T[hd][key] * P[qrow][key]
    __builtin_amdgcn_s_setprio(1);
#pragma unroll
    for (int kk = 0; kk < 2; ++kk) {
      bf16x8 pa = *(const bf16x8*)&Pl[w][lr][16 * kk + 4 * lk];
#pragma unroll
      for (int n = 0; n < 4; ++n) {
        bf16x8 vb = *(const bf16x8*)(&Vbuf[cur][(n * 16 + lr) * 64 + (((kk * 4 + lk) ^ (lr & 7)) << 3)]);
        O[n] = __builtin_amdgcn_mfma_f32_16x16x32_bf16(vb, pa, O[n], 0, 0, 0);
      }
    }
    __builtin_amdgcn_s_setprio(0);
    __syncthreads();
    cur ^= 1;
  }
  float inv = 1.0f / lsum;
  const size_t rowbase = ((size_t)((b << 11) + q0 + w * 16 + lr)) * 1024 + (h << 6);
#pragma unroll
  for (int n = 0; n < 4; ++n) {
    u16x4 o4;
#pragma unroll
    for (int r = 0; r < 4; ++r) o4[r] = f2bf(O[n][r] * inv);
    *(u16x4*)(ctx + rowbase + n * 16 + 4 * lk) = o4;
  }
}

// ---------------------------------------------------------------- launch
extern "C" void kernel_launch(void* const* d_in, const int* in_sizes, int n_in,
                              void* d_out, int out_size, void* d_ws, size_t ws_size,
                              hipStream_t stream) {
  (void)in_sizes; (void)n_in; (void)out_size; (void)ws_size;
  const float* x  = (const float*)d_in[0];
  const float* Wq = (const float*)d_in[1];
  const float* bq = (const float*)d_in[2];
  const float* Wk = (const float*)d_in[3];
  const float* bk = (const float*)d_in[4];
  const float* Wv = (const float*)d_in[5];
  const float* bv = (const float*)d_in[6];
  const float* Wo = (const float*)d_in[7];
  const float* bo = (const float*)d_in[8];
  const float* gq = (const float*)d_in[9];
  const float* gk = (const float*)d_in[10];
  const float* fc = (const float*)d_in[11];
  const float* fs = (const float*)d_in[12];
  float* out = (float*)d_out;
  char* ws = (char*)d_ws;
  u16*  xb  = (u16*)(ws + 0);           //  8 MB  x bf16 [4096][1024]
  u16*  wqb = (u16*)(ws + 8388608);     //  2 MB each, contiguous x4
  u16*  wkb = (u16*)(ws + 10485760);
  u16*  wvb = (u16*)(ws + 12582912);
  u16*  wob = (u16*)(ws + 14680064);
  u16*  Qfb = (u16*)(ws + 16777216);    //  8 MB bf16 [4096][1024] pre-norm q
  u16*  Kfb = (u16*)(ws + 25165824);    //  8 MB
  u16*  Qhb = (u16*)(ws + 33554432);    //  8 MB bf16 [B,H,S,64] (pre-scaled)
  u16*  Khb = (u16*)(ws + 41943040);    //  8 MB bf16 [B,H,S,64]
  u16*  Vtb = (u16*)(ws + 50331648);    //  8 MB bf16 [B,H,64,S] (V transposed)
  u16*  ctx = (u16*)(ws + 58720256);    //  8 MB bf16 [B,S,D]

  f2b_kernel<<<4096, 256, 0, stream>>>(x, xb, 1048576);
  f2bw_kernel<<<dim3(1024, 4), 256, 0, stream>>>(Wq, Wk, Wv, Wo, wqb);
  qkv_gemm<<<dim3(32, 8, 3), 256, 0, stream>>>(xb, wqb, wkb, wvb, bq, bk, bv, Qfb, Kfb, Vtb);
  rmsrope<<<dim3(4096, 2), 256, 0, stream>>>(Qfb, Kfb, gq, gk, fc, fs, Qhb, Khb);
  attn_kernel<<<512, 512, 0, stream>>>(Qhb, Khb, Vtb, ctx);
  proj_gemm<<<dim3(32, 8), 256, 0, stream>>>(ctx, wob, bo, out);
}

// Round 5
// 147.958 us; speedup vs baseline: 1.4882x; 1.0658x over previous
//
#include <hip/hip_runtime.h>

typedef unsigned short u16;
typedef unsigned int u32;
typedef u16 u16x4 __attribute__((ext_vector_type(4)));
typedef u16 u16x8 __attribute__((ext_vector_type(8)));
typedef u32 u32x2 __attribute__((ext_vector_type(2)));
typedef float f32x4 __attribute__((ext_vector_type(4)));
typedef __bf16 bf16x2 __attribute__((ext_vector_type(2)));
typedef __bf16 bf16x8 __attribute__((ext_vector_type(8)));

#define GLOAD16(gp, lp)                                             \
  __builtin_amdgcn_global_load_lds(                                 \
      (const __attribute__((address_space(1))) void*)(gp),          \
      (__attribute__((address_space(3))) void*)(lp), 16, 0, 0)

__device__ __forceinline__ u16 f2bf(float f) {
  unsigned int u = __builtin_bit_cast(unsigned int, f);
  u += 0x7FFFu + ((u >> 16) & 1u);
  return (u16)(u >> 16);
}
__device__ __forceinline__ float bf2f(u16 h) {
  return __builtin_bit_cast(float, (u32)h << 16);
}

// ---------------------------------------------------------------- f32 -> bf16
__global__ __launch_bounds__(256) void f2b_kernel(const float* __restrict__ in,
                                                  u16* __restrict__ out, int n4) {
  int i = blockIdx.x * 256 + threadIdx.x;
  if (i < n4) {
    f32x4 v = *(const f32x4*)(in + (size_t)i * 4);
    u16x4 o;
    o[0] = f2bf(v[0]); o[1] = f2bf(v[1]); o[2] = f2bf(v[2]); o[3] = f2bf(v[3]);
    *(u16x4*)(out + (size_t)i * 4) = o;
  }
}

// all 4 weight matrices in one launch; dst regions contiguous (1M elems each)
__global__ __launch_bounds__(256) void f2bw_kernel(const float* __restrict__ s0,
    const float* __restrict__ s1, const float* __restrict__ s2,
    const float* __restrict__ s3, u16* __restrict__ dst) {
  const int y = blockIdx.y;
  const float* s = (y == 0) ? s0 : ((y == 1) ? s1 : ((y == 2) ? s2 : s3));
  int i = blockIdx.x * 256 + threadIdx.x;
  f32x4 v = *(const f32x4*)(s + (size_t)i * 4);
  u16x4 o;
  o[0] = f2bf(v[0]); o[1] = f2bf(v[1]); o[2] = f2bf(v[2]); o[3] = f2bf(v[3]);
  *(u16x4*)(dst + (size_t)y * 1048576 + (size_t)i * 4) = o;
}

// --------------------------------------------- NT GEMM core: C = A * W^T
// 128x128 tile, BK=32, 256 thr (4 waves). 3-buffer counted-vmcnt pipeline:
// per iter: vmcnt(4) [next tile stays in flight] -> s_barrier -> stage(kt+2)
// -> compute. No vmcnt(0) drain except the last iteration.
__device__ __forceinline__ void gemm_core(const u16* __restrict__ A,
                                          const u16* __restrict__ W,
                                          int bm0, int bn0,
                                          u16* ldsA, u16* ldsB,
                                          f32x4 acc[4][4]) {
  const int tid = threadIdx.x;
  const int l = tid & 63;
  const int lr = l & 15, lk = l >> 4;
  const int w = tid >> 6;
  const int wr = w >> 1, wc = w & 1;
  const int srow = tid >> 2, sko = (tid & 3) << 3;
  auto stage = [&](int kt, int buf) {  // 4 VMEM loads per thread
#pragma unroll
    for (int it = 0; it < 2; ++it) {
      int row = it * 64 + srow;
      GLOAD16(A + (size_t)(bm0 + row) * 1024 + kt * 32 + sko,
              ldsA + buf * 4096 + (it * 256 + tid) * 8);
      GLOAD16(W + (size_t)(bn0 + row) * 1024 + kt * 32 + sko,
              ldsB + buf * 4096 + (it * 256 + tid) * 8);
    }
  };
  stage(0, 0);
  stage(1, 1);
  int cur = 0, nx2 = 2;
  for (int kt = 0; kt < 32; ++kt) {
    if (kt < 31) asm volatile("s_waitcnt vmcnt(4)" ::: "memory");
    else         asm volatile("s_waitcnt vmcnt(0)" ::: "memory");
    __builtin_amdgcn_s_barrier();
    __builtin_amdgcn_sched_barrier(0);
    if (kt + 2 < 32) stage(kt + 2, nx2);
    const u16* lA = ldsA + cur * 4096;
    const u16* lB = ldsB + cur * 4096;
    bf16x8 af[4], bfr[4];
#pragma unroll
    for (int m = 0; m < 4; ++m)
      af[m] = *(const bf16x8*)(lA + (wr * 64 + m * 16 + lr) * 32 + lk * 8);
#pragma unroll
    for (int n = 0; n < 4; ++n)
      bfr[n] = *(const bf16x8*)(lB + (wc * 64 + n * 16 + lr) * 32 + lk * 8);
#pragma unroll
    for (int m = 0; m < 4; ++m)
#pragma unroll
      for (int n = 0; n < 4; ++n)
        acc[m][n] = __builtin_amdgcn_mfma_f32_16x16x32_bf16(af[m], bfr[n], acc[m][n], 0, 0, 0);
    cur = (cur == 2) ? 0 : cur + 1;
    nx2 = (nx2 == 2) ? 0 : nx2 + 1;
  }
}

// --------------------------------------------- fused QKV projection
// z=0: Q -> Qb (bf16 [4096][1024]); z=1: K -> Kb; z=2: V -> V^T bf16 [B,H,64,S]
__global__ __launch_bounds__(256) void qkv_gemm(const u16* __restrict__ xb,
    const u16* __restrict__ wq, const u16* __restrict__ wk, const u16* __restrict__ wv,
    const float* __restrict__ bq, const float* __restrict__ bk, const float* __restrict__ bv,
    u16* __restrict__ Qb, u16* __restrict__ Kb, u16* __restrict__ Vt) {
  __shared__ u16 ldsA[3 * 4096];
  __shared__ u16 ldsB[3 * 4096];
  const int z = blockIdx.z;
  const u16* W = (z == 0) ? wq : ((z == 1) ? wk : wv);
  const float* bias = (z == 0) ? bq : ((z == 1) ? bk : bv);
  const int bm0 = blockIdx.x * 128, bn0 = blockIdx.y * 128;
  const f32x4 zf = {0.f, 0.f, 0.f, 0.f};
  f32x4 acc[4][4];
#pragma unroll
  for (int m = 0; m < 4; ++m)
#pragma unroll
    for (int n = 0; n < 4; ++n) acc[m][n] = zf;
  gemm_core(xb, W, bm0, bn0, ldsA, ldsB, acc);
  const int tid = threadIdx.x, l = tid & 63, lr = l & 15, lk = l >> 4;
  const int w = tid >> 6, wr = w >> 1, wc = w & 1;
  float bcol[4];
#pragma unroll
  for (int n = 0; n < 4; ++n) bcol[n] = bias[bn0 + wc * 64 + n * 16 + lr];
  if (z < 2) {
    u16* outp = z ? Kb : Qb;
#pragma unroll
    for (int m = 0; m < 4; ++m)
#pragma unroll
      for (int n = 0; n < 4; ++n)
#pragma unroll
        for (int r = 0; r < 4; ++r) {
          int row = bm0 + wr * 64 + m * 16 + lk * 4 + r;
          int col = bn0 + wc * 64 + n * 16 + lr;
          outp[(size_t)row * 1024 + col] = f2bf(acc[m][n][r] + bcol[n]);
        }
  } else {
    // V^T: [B,H,64,2048]; 4 consecutive s per lane -> u16x4 store
#pragma unroll
    for (int m = 0; m < 4; ++m)
#pragma unroll
      for (int n = 0; n < 4; ++n) {
        int row = bm0 + wr * 64 + m * 16 + lk * 4;   // s base (r = 0..3)
        int col = bn0 + wc * 64 + n * 16 + lr;
        int b = row >> 11, s = row & 2047, hh = col >> 6, hd = col & 63;
        u16x4 o;
#pragma unroll
        for (int r = 0; r < 4; ++r) o[r] = f2bf(acc[m][n][r] + bcol[n]);
        *(u16x4*)(Vt + (((size_t)((b * 16 + hh) * 64 + hd)) << 11) + s) = o;
      }
  }
}

// --------------------------------------------- output projection
__global__ __launch_bounds__(256) void proj_gemm(const u16* __restrict__ ctx,
    const u16* __restrict__ wo, const float* __restrict__ bo, float* __restrict__ out) {
  __shared__ u16 ldsA[3 * 4096];
  __shared__ u16 ldsB[3 * 4096];
  const int bm0 = blockIdx.x * 128, bn0 = blockIdx.y * 128;
  const f32x4 zf = {0.f, 0.f, 0.f, 0.f};
  f32x4 acc[4][4];
#pragma unroll
  for (int m = 0; m < 4; ++m)
#pragma unroll
    for (int n = 0; n < 4; ++n) acc[m][n] = zf;
  gemm_core(ctx, wo, bm0, bn0, ldsA, ldsB, acc);
  const int tid = threadIdx.x, l = tid & 63, lr = l & 15, lk = l >> 4;
  const int w = tid >> 6, wr = w >> 1, wc = w & 1;
  float bcol[4];
#pragma unroll
  for (int n = 0; n < 4; ++n) bcol[n] = bo[bn0 + wc * 64 + n * 16 + lr];
#pragma unroll
  for (int m = 0; m < 4; ++m)
#pragma unroll
    for (int n = 0; n < 4; ++n)
#pragma unroll
      for (int r = 0; r < 4; ++r) {
        int row = bm0 + wr * 64 + m * 16 + lk * 4 + r;
        int col = bn0 + wc * 64 + n * 16 + lr;
        out[(size_t)row * 1024 + col] = acc[m][n][r] + bcol[n];
      }
}

// --------------------------------------------- RMSNorm + RoPE (bf16 in/out)
// which==0 (q): also fold 0.125*log2(e) so attn scores are exp2-domain ready.
__global__ __launch_bounds__(256) void rmsrope(const u16* __restrict__ Qb,
    const u16* __restrict__ Kb, const float* __restrict__ gq, const float* __restrict__ gk,
    const float* __restrict__ fc, const float* __restrict__ fs,
    u16* __restrict__ Qh, u16* __restrict__ Kh) {
  const int row = blockIdx.x;
  const int which = blockIdx.y;
  const u16* src = (which ? Kb : Qb) + (size_t)row * 1024;
  const float* g = which ? gk : gq;
  u16* dst = which ? Kh : Qh;
  const int t = threadIdx.x;
  u16x4 raw = *(const u16x4*)(src + t * 4);
  float v0 = bf2f(raw[0]), v1 = bf2f(raw[1]), v2 = bf2f(raw[2]), v3 = bf2f(raw[3]);
  float ss = v0 * v0 + v1 * v1 + v2 * v2 + v3 * v3;
#pragma unroll
  for (int mm = 1; mm < 64; mm <<= 1) ss += __shfl_xor(ss, mm);
  __shared__ float red[4];
  if ((t & 63) == 0) red[t >> 6] = ss;
  __syncthreads();
  float rstd = rsqrtf((red[0] + red[1] + red[2] + red[3]) * (1.0f / 1024.0f) + 1e-6f);
  if (!which) rstd *= 0.18033688011112042f;   // 0.125 * log2(e) folded into q
  int d = t * 4, hh = d >> 6, dh = d & 63, p = dh >> 1;
  int s = row & 2047, b = row >> 11;
  float c0 = fc[(s << 5) + p], s0 = fs[(s << 5) + p];
  float c1 = fc[(s << 5) + p + 1], s1 = fs[(s << 5) + p + 1];
  float x0 = v0 * rstd * g[d];
  float x1 = v1 * rstd * g[d + 1];
  float x2 = v2 * rstd * g[d + 2];
  float x3 = v3 * rstd * g[d + 3];
  u16x4 o;
  o[0] = f2bf(x0 * c0 - x1 * s0);
  o[1] = f2bf(x0 * s0 + x1 * c0);
  o[2] = f2bf(x2 * c1 - x3 * s1);
  o[3] = f2bf(x2 * s1 + x3 * c1);
  *(u16x4*)(dst + ((size_t)((b << 4) + hh) * 2048 + s) * 64 + dh) = o;
}

// --------------------------------------------- flash attention (non-causal)
// 512 blocks x 512 thr, 8 waves x 16 q-rows. Swapped-operand MFMA; scores in
// exp2 domain. 3-buffer counted-vmcnt pipeline (no vmcnt(0) drain in loop).
__global__ __launch_bounds__(512, 4) void attn_kernel(const u16* __restrict__ Qh,
    const u16* __restrict__ Kh, const u16* __restrict__ Vt, u16* __restrict__ ctx) {
  __shared__ u16 Kbuf[3][4096];   // [key][64] linear, source-XOR-swizzled chunks
  __shared__ u16 Vbuf[3][4096];   // [hd][64 keys] linear, source-XOR-swizzled
  __shared__ __attribute__((aligned(16))) u32 Pl[8][16][36];  // per-wave P bf16x2
  const int tid = threadIdx.x;
  const int w = tid >> 6, l = tid & 63, lr = l & 15, lk = l >> 4;
  const int id = blockIdx.x;
  const int qt = (id >> 3) & 15;
  const int hb = (id & 7) | ((id >> 7) << 3);
  const int h = hb & 15, b = hb >> 4;
  const int bh = b * 16 + h;
  const u16* Q = Qh + (size_t)bh * 2048 * 64;
  const u16* K = Kh + (size_t)bh * 2048 * 64;
  const u16* V = Vt + (size_t)bh * 64 * 2048;
  const int q0 = qt * 128;
  const int srow = tid >> 3;
  const int kslot = (tid & 7) ^ (srow & 7);
  bf16x8 qf[2];
#pragma unroll
  for (int kh = 0; kh < 2; ++kh)
    qf[kh] = *(const bf16x8*)(Q + (size_t)(q0 + w * 16 + lr) * 64 + kh * 32 + lk * 8);
  const f32x4 zf = {0.f, 0.f, 0.f, 0.f};
  f32x4 O[4];                                   // O[hd=16n+4lk+r][qrow=lr]
  float Mrun = -1e30f, lsum = 0.f;
#pragma unroll
  for (int n = 0; n < 4; ++n) O[n] = zf;
  // prologue: stage tiles 0 and 1 (2 VMEM loads per thread per tile)
  GLOAD16(K + ((size_t)srow << 6) + kslot * 8, &Kbuf[0][tid * 8]);
  GLOAD16(V + ((size_t)srow << 11) + kslot * 8, &Vbuf[0][tid * 8]);
  GLOAD16(K + ((size_t)(64 + srow) << 6) + kslot * 8, &Kbuf[1][tid * 8]);
  GLOAD16(V + ((size_t)srow << 11) + 64 + kslot * 8, &Vbuf[1][tid * 8]);
  int cur = 0, nx2 = 2;
  for (int kb = 0; kb < 32; ++kb) {
    if (kb < 31) asm volatile("s_waitcnt vmcnt(2)" ::: "memory");
    else         asm volatile("s_waitcnt vmcnt(0)" ::: "memory");
    __builtin_amdgcn_s_barrier();
    __builtin_amdgcn_sched_barrier(0);
    if (kb + 2 < 32) {
      GLOAD16(K + ((size_t)((kb + 2) * 64 + srow) << 6) + kslot * 8, &Kbuf[nx2][tid * 8]);
      GLOAD16(V + ((size_t)srow << 11) + (kb + 2) * 64 + kslot * 8, &Vbuf[nx2][tid * 8]);
    }
    // QK^T swapped: sc[n][r] = S[qrow=lr][key = 16n + 4lk + r]  (exp2 domain)
    f32x4 sc[4];
#pragma unroll
    for (int n = 0; n < 4; ++n) sc[n] = zf;
    __builtin_amdgcn_s_setprio(1);
#pragma unroll
    for (int n = 0; n < 4; ++n)
#pragma unroll
      for (int kh = 0; kh < 2; ++kh) {
        bf16x8 kf = *(const bf16x8*)(&Kbuf[cur][(n * 16 + lr) * 64 + (((kh * 4 + lk) ^ (lr & 7)) << 3)]);
        sc[n] = __builtin_amdgcn_mfma_f32_16x16x32_bf16(kf, qf[kh], sc[n], 0, 0, 0);
      }
    __builtin_amdgcn_s_setprio(0);
    // online softmax, lane-local except 2+2 shfl_xor
    float bm = fmaxf(fmaxf(sc[0][0], sc[0][1]), fmaxf(sc[0][2], sc[0][3]));
#pragma unroll
    for (int n = 1; n < 4; ++n)
      bm = fmaxf(bm, fmaxf(fmaxf(sc[n][0], sc[n][1]), fmaxf(sc[n][2], sc[n][3])));
    bm = fmaxf(bm, __shfl_xor(bm, 16));
    bm = fmaxf(bm, __shfl_xor(bm, 32));
    if (!__all(bm <= Mrun + 1.4427f)) {         // defer-max (T13), exp2 units
      float nM = fmaxf(Mrun, bm);
      float f = exp2f(Mrun - nM);
      lsum *= f;
#pragma unroll
      for (int n = 0; n < 4; ++n)
#pragma unroll
        for (int r = 0; r < 4; ++r) O[n][r] *= f;
      Mrun = nM;
    }
    float rs = 0.f;
#pragma unroll
    for (int n = 0; n < 4; ++n) {
      u32 pw[2];
#pragma unroll
      for (int c = 0; c < 2; ++c) {
        float p0 = exp2f(sc[n][2 * c] - Mrun);
        float p1 = exp2f(sc[n][2 * c + 1] - Mrun);
        rs += p0 + p1;
        bf16x2 pp;
        pp[0] = (__bf16)p0; pp[1] = (__bf16)p1;
        pw[c] = __builtin_bit_cast(u32, pp);
      }
      u32x2 pv = {pw[0], pw[1]};
      *(u32x2*)&Pl[w][lr][8 * n + 2 * lk] = pv;
    }
    rs += __shfl_xor(rs, 16);
    rs += __shfl_xor(rs, 32);
    lsum += rs;
    // PV swapped: O[hd][qrow] += V^T[hd][key] * P[qrow][key]
    __builtin_amdgcn_s_setprio(1);
#pragma unroll
    for (int kk = 0; kk < 2; ++kk) {
      bf16x8 pa = *(const bf16x8*)&Pl[w][lr][16 * kk + 4 * lk];
#pragma unroll
      for (int n = 0; n < 4; ++n) {
        bf16x8 vb = *(const bf16x8*)(&Vbuf[cur][(n * 16 + lr) * 64 + (((kk * 4 + lk) ^ (lr & 7)) << 3)]);
        O[n] = __builtin_amdgcn_mfma_f32_16x16x32_bf16(vb, pa, O[n], 0, 0, 0);
      }
    }
    __builtin_amdgcn_s_setprio(0);
    cur = (cur == 2) ? 0 : cur + 1;
    nx2 = (nx2 == 2) ? 0 : nx2 + 1;
  }
  float inv = 1.0f / lsum;
  const size_t rowbase = ((size_t)((b << 11) + q0 + w * 16 + lr)) * 1024 + (h << 6);
#pragma unroll
  for (int n = 0; n < 4; ++n) {
    u16x4 o4;
#pragma unroll
    for (int r = 0; r < 4; ++r) o4[r] = f2bf(O[n][r] * inv);
    *(u16x4*)(ctx + rowbase + n * 16 + 4 * lk) = o4;
  }
}

// ---------------------------------------------------------------- launch
extern "C" void kernel_launch(void* const* d_in, const int* in_sizes, int n_in,
                              void* d_out, int out_size, void* d_ws, size_t ws_size,
                              hipStream_t stream) {
  (void)in_sizes; (void)n_in; (void)out_size; (void)ws_size;
  const float* x  = (const float*)d_in[0];
  const float* Wq = (const float*)d_in[1];
  const float* bq = (const float*)d_in[2];
  const float* Wk = (const float*)d_in[3];
  const float* bk = (const float*)d_in[4];
  const float* Wv = (const float*)d_in[5];
  const float* bv = (const float*)d_in[6];
  const float* Wo = (const float*)d_in[7];
  const float* bo = (const float*)d_in[8];
  const float* gq = (const float*)d_in[9];
  const float* gk = (const float*)d_in[10];
  const float* fc = (const float*)d_in[11];
  const float* fs = (const float*)d_in[12];
  float* out = (float*)d_out;
  char* ws = (char*)d_ws;
  u16*  xb  = (u16*)(ws + 0);           //  8 MB  x bf16 [4096][1024]
  u16*  wqb = (u16*)(ws + 8388608);     //  2 MB each, contiguous x4
  u16*  wkb = (u16*)(ws + 10485760);
  u16*  wvb = (u16*)(ws + 12582912);
  u16*  wob = (u16*)(ws + 14680064);
  u16*  Qfb = (u16*)(ws + 16777216);    //  8 MB bf16 [4096][1024] pre-norm q
  u16*  Kfb = (u16*)(ws + 25165824);    //  8 MB
  u16*  Qhb = (u16*)(ws + 33554432);    //  8 MB bf16 [B,H,S,64] (pre-scaled)
  u16*  Khb = (u16*)(ws + 41943040);    //  8 MB bf16 [B,H,S,64]
  u16*  Vtb = (u16*)(ws + 50331648);    //  8 MB bf16 [B,H,64,S] (V transposed)
  u16*  ctx = (u16*)(ws + 58720256);    //  8 MB bf16 [B,S,D]

  f2b_kernel<<<4096, 256, 0, stream>>>(x, xb, 1048576);
  f2bw_kernel<<<dim3(1024, 4), 256, 0, stream>>>(Wq, Wk, Wv, Wo, wqb);
  qkv_gemm<<<dim3(32, 8, 3), 256, 0, stream>>>(xb, wqb, wkb, wvb, bq, bk, bv, Qfb, Kfb, Vtb);
  rmsrope<<<dim3(4096, 2), 256, 0, stream>>>(Qfb, Kfb, gq, gk, fc, fs, Qhb, Khb);
  attn_kernel<<<512, 512, 0, stream>>>(Qhb, Khb, Vtb, ctx);
  proj_gemm<<<dim3(32, 8), 256, 0, stream>>>(ctx, wob, bo, out);
}